// Round 6
// baseline (376.035 us; speedup 1.0000x reference)
//
#include <hip/hip_runtime.h>
#include <hip/hip_bf16.h>

// Problem: B=4, L=2048, D_MODEL=1024, H=16, D_QKV=64.
// Reference einsum 'bhlk,blhd->blhd' contracts k over logits only; softmax sums to 1,
// so attention output == v and the net reduces to:
//   out = x @ Wc + fc_b,  Wc[m][j] = sum_{hd} w_v[h][m][d] * fc_w[j][hd]
// Single fused kernel (regular launch):
//   phase 1: blocks 0-255 fold Wc^T (software-pipelined K loop) || blocks 256-511 cast x->bf16
//   manual device-scope barrier (counter in d_ws, memset-0 by a prior graph node;
//     512 blocks = exactly 2/CU via __launch_bounds__(256,2) + 32KB LDS -> all co-resident)
//   phase 2: all 512 blocks run BK=64 m97-style GEMM out = xb @ wcT^T + fcb.

typedef __attribute__((ext_vector_type(8))) short bf16x8;
typedef __attribute__((ext_vector_type(4))) float f32x4;

__device__ __forceinline__ f32x4 mfma16(bf16x8 a, bf16x8 b, f32x4 c) {
  return __builtin_amdgcn_mfma_f32_16x16x32_bf16(a, b, c, 0, 0, 0);
}

// fp32 -> bf16 bits, round-to-nearest-even
__device__ __forceinline__ unsigned short f2b(float f) {
  unsigned int u = __builtin_bit_cast(unsigned int, f);
  return (unsigned short)((u + 0x7fffu + ((u >> 16) & 1u)) >> 16);
}

__device__ __forceinline__ bf16x8 cvt8(float4 a, float4 b) {
  bf16x8 r;
  r[0] = (short)f2b(a.x); r[1] = (short)f2b(a.y); r[2] = (short)f2b(a.z); r[3] = (short)f2b(a.w);
  r[4] = (short)f2b(b.x); r[5] = (short)f2b(b.y); r[6] = (short)f2b(b.z); r[7] = (short)f2b(b.w);
  return r;
}

// async global->LDS, 16 B per lane (m97 pattern; LDS dest = wave-uniform base + lane*16)
__device__ __forceinline__ void gld_lds16(const void* g, void* l) {
  __builtin_amdgcn_global_load_lds((const __attribute__((address_space(1))) unsigned int*)g,
                                   (__attribute__((address_space(3))) unsigned int*)l, 16, 0, 0);
}

__global__ __launch_bounds__(256, 2) void fused_all(const float* __restrict__ x,
                                                    const float* __restrict__ wv,
                                                    const float* __restrict__ fcw,
                                                    const float* __restrict__ fcb,
                                                    unsigned short* __restrict__ xb,
                                                    unsigned short* __restrict__ wcT,
                                                    unsigned int* __restrict__ barrier_cnt,
                                                    float* __restrict__ out) {
  __shared__ __align__(16) unsigned short As[2 * 128 * 32];  // phase-2 only (32 KB total)
  __shared__ __align__(16) unsigned short Bs[2 * 128 * 32];
  int bid = blockIdx.x, t = threadIdx.x;
  int wid = t >> 6, lane = t & 63, l16 = lane & 15, quad = lane >> 4;

  // ---------------- phase 1 ----------------
  if (bid < 256) {
    // fold: wcT[j][m] = sum_{hd} fcw[j][hd] * wv[hd>>6][m][hd&63]; 64x64 tile, 4 waves 2x2.
    // K-loop software-pipelined: prefetch next 32-k batch before current MFMAs.
    int wr = wid >> 1, wc = wid & 1;
    int row0 = (bid >> 4) * 64 + wr * 32;   // j
    int col0 = (bid & 15) * 64 + wc * 32;   // m
    f32x4 acc[2][2];
#pragma unroll
    for (int a = 0; a < 2; a++)
#pragma unroll
      for (int b = 0; b < 2; b++) acc[a][b] = (f32x4){0.f, 0.f, 0.f, 0.f};

    float4 A0[2][2], B0[2][2];
#define LOADK(kk, Ad, Bd)                                                            \
    {                                                                                \
      int h_ = (kk) >> 6, d_ = (kk) & 63;                                            \
      _Pragma("unroll")                                                              \
      for (int rt = 0; rt < 2; rt++) {                                               \
        const float* pa = fcw + (row0 + rt * 16 + l16) * 1024 + (kk);                \
        Ad[rt][0] = *reinterpret_cast<const float4*>(pa);                            \
        Ad[rt][1] = *reinterpret_cast<const float4*>(pa + 4);                        \
      }                                                                              \
      _Pragma("unroll")                                                              \
      for (int ct = 0; ct < 2; ct++) {                                               \
        const float* pb = wv + h_ * 65536 + (col0 + ct * 16 + l16) * 64 + d_;        \
        Bd[ct][0] = *reinterpret_cast<const float4*>(pb);                            \
        Bd[ct][1] = *reinterpret_cast<const float4*>(pb + 4);                        \
      }                                                                              \
    }

    LOADK(quad * 8, A0, B0);
    for (int k0 = 0; k0 < 1024; k0 += 32) {
      float4 A1[2][2], B1[2][2];
      if (k0 < 992) LOADK(k0 + 32 + quad * 8, A1, B1);
      bf16x8 af[2], bfr[2];
#pragma unroll
      for (int rt = 0; rt < 2; rt++) af[rt] = cvt8(A0[rt][0], A0[rt][1]);
#pragma unroll
      for (int ct = 0; ct < 2; ct++) bfr[ct] = cvt8(B0[ct][0], B0[ct][1]);
#pragma unroll
      for (int rt = 0; rt < 2; rt++)
#pragma unroll
        for (int ct = 0; ct < 2; ct++) acc[rt][ct] = mfma16(af[rt], bfr[ct], acc[rt][ct]);
#pragma unroll
      for (int a = 0; a < 2; a++)
#pragma unroll
        for (int b = 0; b < 2; b++) { A0[a][b] = A1[a][b]; B0[a][b] = B1[a][b]; }
    }
#undef LOADK
#pragma unroll
    for (int rt = 0; rt < 2; rt++)
#pragma unroll
      for (int ct = 0; ct < 2; ct++) {
        int j0 = row0 + rt * 16 + quad * 4;
        int m = col0 + ct * 16 + l16;
#pragma unroll
        for (int r = 0; r < 4; r++) wcT[(j0 + r) * 1024 + m] = f2b(acc[rt][ct][r]);
      }
  } else {
    // cast: x fp32 -> bf16, 32768 elems per block (contiguous), 16-B ld/st.
    int base0 = (bid - 256) << 15;
#pragma unroll
    for (int i = 0; i < 16; i++) {
      int idx = base0 + i * 2048 + t * 8;
      float4 a = *reinterpret_cast<const float4*>(x + idx);
      float4 b = *reinterpret_cast<const float4*>(x + idx + 4);
      *reinterpret_cast<bf16x8*>(xb + idx) = cvt8(a, b);
    }
  }

  // ---------------- manual grid barrier (counter pre-zeroed by hipMemsetAsync) -------------
  __threadfence();                 // flush this block's wcT/xb stores to device scope (L3)
  __syncthreads();
  if (t == 0) {
    __hip_atomic_fetch_add(barrier_cnt, 1u, __ATOMIC_ACQ_REL, __HIP_MEMORY_SCOPE_AGENT);
    while (__hip_atomic_load(barrier_cnt, __ATOMIC_ACQUIRE, __HIP_MEMORY_SCOPE_AGENT) < 512u)
      __builtin_amdgcn_s_sleep(8);
  }
  __syncthreads();
  __threadfence();                 // acquire: discard stale L1 before reading xb/wcT

  // ---------------- phase 2: out = xb @ wcT^T + fcb ----------------
  // N-fastest mapping: 8 consecutive blocks share one A M-tile; B (2 MB) stays L2-hot.
  int row0 = (bid >> 3) * 128;   // M tile
  int col0 = (bid & 7) * 128;    // N tile
  int wr = wid >> 1, wc = wid & 1;

  // staging: wave w issues 4 gld_lds16; blk = w*4+j covers LDS [blk*1KB, +1KB) =
  // slab blk>>3, rows (blk&7)*16..+15; lane -> row + lane>>2, k-quad lane&3.
  int w4 = wid * 4;
  const unsigned short* Ap[4];
  const unsigned short* Bp[4];
#pragma unroll
  for (int j = 0; j < 4; j++) {
    int blk = w4 + j;
    int s = blk >> 3, r0 = (blk & 7) * 16;
    int row = r0 + (lane >> 2), kq = lane & 3;
    Ap[j] = xb + (row0 + row) * 1024 + s * 32 + kq * 8;
    Bp[j] = wcT + (col0 + row) * 1024 + s * 32 + kq * 8;
  }

  f32x4 acc[16];
#pragma unroll
  for (int i = 0; i < 16; i++) acc[i] = (f32x4){0.f, 0.f, 0.f, 0.f};

  for (int k0 = 0; k0 < 1024; k0 += 64) {
    __syncthreads();
#pragma unroll
    for (int j = 0; j < 4; j++) {
      int off = (w4 + j) * 512 + lane * 8;
      gld_lds16(Ap[j] + k0, &As[off]);
      gld_lds16(Bp[j] + k0, &Bs[off]);
    }
    __syncthreads();
#pragma unroll
    for (int s = 0; s < 2; s++) {
      bf16x8 af[4], bfr[4];
#pragma unroll
      for (int rt = 0; rt < 4; rt++)
        af[rt] = *reinterpret_cast<const bf16x8*>(&As[s * 4096 + (wr * 64 + rt * 16 + l16) * 32 + quad * 8]);
#pragma unroll
      for (int ct = 0; ct < 4; ct++)
        bfr[ct] = *reinterpret_cast<const bf16x8*>(&Bs[s * 4096 + (wc * 64 + ct * 16 + l16) * 32 + quad * 8]);
#pragma unroll
      for (int rt = 0; rt < 4; rt++)
#pragma unroll
        for (int ct = 0; ct < 4; ct++)
          acc[rt * 4 + ct] = mfma16(af[rt], bfr[ct], acc[rt * 4 + ct]);
    }
  }

#pragma unroll
  for (int ct = 0; ct < 4; ct++) {
    int j = col0 + wc * 64 + ct * 16 + l16;
    float bias = fcb[j];
#pragma unroll
    for (int rt = 0; rt < 4; rt++) {
      int i0 = row0 + wr * 64 + rt * 16 + quad * 4;
      f32x4 a = acc[rt * 4 + ct];
#pragma unroll
      for (int r = 0; r < 4; r++) out[(i0 + r) * 1024 + j] = a[r] + bias;
    }
  }
}

extern "C" void kernel_launch(void* const* d_in, const int* in_sizes, int n_in,
                              void* d_out, int out_size, void* d_ws, size_t ws_size,
                              hipStream_t stream) {
  const float* x   = (const float*)d_in[0];
  // d_in[1] mask, d_in[2] w_q, d_in[3] w_k: dead per reference semantics
  const float* wv  = (const float*)d_in[4];
  const float* fcw = (const float*)d_in[5];
  const float* fcb = (const float*)d_in[6];
  float* out = (float*)d_out;

  char* ws = (char*)d_ws;
  unsigned short* xb  = (unsigned short*)(ws);              // 16 MB (8192x1024 bf16)
  unsigned short* wcT = (unsigned short*)(ws + 16777216);   // 2 MB  (1024x1024 bf16)
  unsigned int* bar   = (unsigned int*)(ws + 18874368);     // barrier counter

  hipMemsetAsync(bar, 0, 64, stream);                       // reset barrier every call
  fused_all<<<512, 256, 0, stream>>>(x, wv, fcw, fcb, xb, wcT, bar, out);
}

// Round 7
// 151.023 us; speedup vs baseline: 2.4899x; 2.4899x over previous
//
#include <hip/hip_runtime.h>
#include <hip/hip_bf16.h>

// Problem: B=4, L=2048, D_MODEL=1024, H=16, D_QKV=64.
// Reference einsum 'bhlk,blhd->blhd' contracts k over logits only; softmax sums to 1,
// so attention output == v and the net reduces to:
//   out = x @ Wc + fc_b,  Wc[m][j] = sum_{hd} w_v[h][m][d] * fc_w[j][hd]
// Two launches (NO grid barrier — round-6 showed agent-scope spin barriers cost ~250us on
// non-coherent per-XCD L2):
//   prep: blocks 0-255 fold Wc^T (pipelined K loop) || blocks 256-511 cast x->bf16 (independent)
//   final_gemm: 128x64 tiles, 1024 blocks (4/CU via __launch_bounds__(256,4), 24KB LDS)
//               -> 2x latency overlap vs round-4's 512-block 128x128 version.

typedef __attribute__((ext_vector_type(8))) short bf16x8;
typedef __attribute__((ext_vector_type(4))) float f32x4;

__device__ __forceinline__ f32x4 mfma16(bf16x8 a, bf16x8 b, f32x4 c) {
  return __builtin_amdgcn_mfma_f32_16x16x32_bf16(a, b, c, 0, 0, 0);
}

// fp32 -> bf16 bits, round-to-nearest-even
__device__ __forceinline__ unsigned short f2b(float f) {
  unsigned int u = __builtin_bit_cast(unsigned int, f);
  return (unsigned short)((u + 0x7fffu + ((u >> 16) & 1u)) >> 16);
}

__device__ __forceinline__ bf16x8 cvt8(float4 a, float4 b) {
  bf16x8 r;
  r[0] = (short)f2b(a.x); r[1] = (short)f2b(a.y); r[2] = (short)f2b(a.z); r[3] = (short)f2b(a.w);
  r[4] = (short)f2b(b.x); r[5] = (short)f2b(b.y); r[6] = (short)f2b(b.z); r[7] = (short)f2b(b.w);
  return r;
}

// async global->LDS, 16 B per lane (m97 pattern; LDS dest = wave-uniform base + lane*16)
__device__ __forceinline__ void gld_lds16(const void* g, void* l) {
  __builtin_amdgcn_global_load_lds((const __attribute__((address_space(1))) unsigned int*)g,
                                   (__attribute__((address_space(3))) unsigned int*)l, 16, 0, 0);
}

// prep: blocks 0-255 fold Wc^T; blocks 256-511 cast x->bf16. No inter-block dependency.
__global__ __launch_bounds__(256) void prep(const float* __restrict__ x,
                                            const float* __restrict__ wv,
                                            const float* __restrict__ fcw,
                                            unsigned short* __restrict__ xb,
                                            unsigned short* __restrict__ wcT) {
  int bid = blockIdx.x, t = threadIdx.x;
  int wid = t >> 6, lane = t & 63, l16 = lane & 15, quad = lane >> 4;

  if (bid < 256) {
    // fold: wcT[j][m] = sum_{hd} fcw[j][hd] * wv[hd>>6][m][hd&63]; 64x64 tile, 4 waves 2x2.
    // Software-pipelined: prefetch next 32-k batch before current MFMAs.
    int wr = wid >> 1, wc = wid & 1;
    int row0 = (bid >> 4) * 64 + wr * 32;   // j
    int col0 = (bid & 15) * 64 + wc * 32;   // m
    f32x4 acc[2][2];
#pragma unroll
    for (int a = 0; a < 2; a++)
#pragma unroll
      for (int b = 0; b < 2; b++) acc[a][b] = (f32x4){0.f, 0.f, 0.f, 0.f};

    float4 A0[2][2], B0[2][2];
#define LOADK(kk, Ad, Bd)                                                            \
    {                                                                                \
      int h_ = (kk) >> 6, d_ = (kk) & 63;                                            \
      _Pragma("unroll")                                                              \
      for (int rt = 0; rt < 2; rt++) {                                               \
        const float* pa = fcw + (row0 + rt * 16 + l16) * 1024 + (kk);                \
        Ad[rt][0] = *reinterpret_cast<const float4*>(pa);                            \
        Ad[rt][1] = *reinterpret_cast<const float4*>(pa + 4);                        \
      }                                                                              \
      _Pragma("unroll")                                                              \
      for (int ct = 0; ct < 2; ct++) {                                               \
        const float* pb = wv + h_ * 65536 + (col0 + ct * 16 + l16) * 64 + d_;        \
        Bd[ct][0] = *reinterpret_cast<const float4*>(pb);                            \
        Bd[ct][1] = *reinterpret_cast<const float4*>(pb + 4);                        \
      }                                                                              \
    }
    LOADK(quad * 8, A0, B0);
    for (int k0 = 0; k0 < 1024; k0 += 32) {
      float4 A1[2][2], B1[2][2];
      if (k0 < 992) LOADK(k0 + 32 + quad * 8, A1, B1);
      bf16x8 af[2], bfr[2];
#pragma unroll
      for (int rt = 0; rt < 2; rt++) af[rt] = cvt8(A0[rt][0], A0[rt][1]);
#pragma unroll
      for (int ct = 0; ct < 2; ct++) bfr[ct] = cvt8(B0[ct][0], B0[ct][1]);
#pragma unroll
      for (int rt = 0; rt < 2; rt++)
#pragma unroll
        for (int ct = 0; ct < 2; ct++) acc[rt][ct] = mfma16(af[rt], bfr[ct], acc[rt][ct]);
#pragma unroll
      for (int a = 0; a < 2; a++)
#pragma unroll
        for (int b = 0; b < 2; b++) { A0[a][b] = A1[a][b]; B0[a][b] = B1[a][b]; }
    }
#undef LOADK
#pragma unroll
    for (int rt = 0; rt < 2; rt++)
#pragma unroll
      for (int ct = 0; ct < 2; ct++) {
        int j0 = row0 + rt * 16 + quad * 4;
        int m = col0 + ct * 16 + l16;
#pragma unroll
        for (int r = 0; r < 4; r++) wcT[(j0 + r) * 1024 + m] = f2b(acc[rt][ct][r]);
      }
  } else {
    // cast: x fp32 -> bf16, 32768 elems per block (contiguous), 16-B ld/st.
    int base0 = (bid - 256) << 15;
#pragma unroll
    for (int i = 0; i < 16; i++) {
      int idx = base0 + i * 2048 + t * 8;
      float4 a = *reinterpret_cast<const float4*>(x + idx);
      float4 b = *reinterpret_cast<const float4*>(x + idx + 4);
      *reinterpret_cast<bf16x8*>(xb + idx) = cvt8(a, b);
    }
  }
}

// out[i][j] = sum_m xb[i][m]*wcT[j][m] + fcb[j].  M=8192,N=1024,K=1024.
// 128x64 tile, BK=64 (two 32-k slabs), 1024 blocks N-fastest (16 blocks share an A M-tile).
// LDS 24KB, target 4 blocks/CU for latency hiding (this GEMM is latency-bound: r2 MfmaUtil 9%).
__global__ __launch_bounds__(256, 4) void final_gemm(const unsigned short* __restrict__ xb,
                                                     const unsigned short* __restrict__ wcT,
                                                     const float* __restrict__ fcb,
                                                     float* __restrict__ out) {
  __shared__ __align__(16) unsigned short As[2 * 128 * 32];  // 16 KB  [slab][row][32]
  __shared__ __align__(16) unsigned short Bs[2 * 64 * 32];   //  8 KB
  int t = threadIdx.x, wid = t >> 6, lane = t & 63, l16 = lane & 15, quad = lane >> 4;
  int wr = wid >> 1, wc = wid & 1;
  int row0 = (blockIdx.x >> 4) * 128;   // M tile (64)
  int col0 = (blockIdx.x & 15) * 64;    // N tile (16) — fastest: B stays L2-hot

  // A staging: 16 x 1KB chunks; blk = wid*4+j: slab blk>>3, rows (blk&7)*16 + lane>>2, kq lane&3.
  // B staging:  8 x 1KB chunks; blk = wid*2+j: slab blk>>2, rows (blk&3)*16 + lane>>2, kq lane&3.
  int w4 = wid * 4, w2 = wid * 2;
  const unsigned short* Ap[4];
  const unsigned short* Bp[2];
#pragma unroll
  for (int j = 0; j < 4; j++) {
    int blk = w4 + j, s = blk >> 3;
    int row = (blk & 7) * 16 + (lane >> 2), kq = lane & 3;
    Ap[j] = xb + (row0 + row) * 1024 + s * 32 + kq * 8;
  }
#pragma unroll
  for (int j = 0; j < 2; j++) {
    int blk = w2 + j, s = blk >> 2;
    int row = (blk & 3) * 16 + (lane >> 2), kq = lane & 3;
    Bp[j] = wcT + (col0 + row) * 1024 + s * 32 + kq * 8;
  }

  f32x4 acc[4][2];
#pragma unroll
  for (int rt = 0; rt < 4; rt++)
#pragma unroll
    for (int ct = 0; ct < 2; ct++) acc[rt][ct] = (f32x4){0.f, 0.f, 0.f, 0.f};

  for (int k0 = 0; k0 < 1024; k0 += 64) {
    __syncthreads();
#pragma unroll
    for (int j = 0; j < 4; j++) gld_lds16(Ap[j] + k0, &As[(w4 + j) * 512 + lane * 8]);
#pragma unroll
    for (int j = 0; j < 2; j++) gld_lds16(Bp[j] + k0, &Bs[(w2 + j) * 512 + lane * 8]);
    __syncthreads();
#pragma unroll
    for (int s = 0; s < 2; s++) {
      bf16x8 af[4], bfr[2];
#pragma unroll
      for (int rt = 0; rt < 4; rt++)
        af[rt] = *reinterpret_cast<const bf16x8*>(&As[s * 4096 + (wr * 64 + rt * 16 + l16) * 32 + quad * 8]);
#pragma unroll
      for (int ct = 0; ct < 2; ct++)
        bfr[ct] = *reinterpret_cast<const bf16x8*>(&Bs[s * 2048 + (wc * 32 + ct * 16 + l16) * 32 + quad * 8]);
#pragma unroll
      for (int rt = 0; rt < 4; rt++)
#pragma unroll
        for (int ct = 0; ct < 2; ct++)
          acc[rt][ct] = mfma16(af[rt], bfr[ct], acc[rt][ct]);
    }
  }

#pragma unroll
  for (int ct = 0; ct < 2; ct++) {
    int j = col0 + wc * 32 + ct * 16 + l16;
    float bias = fcb[j];
#pragma unroll
    for (int rt = 0; rt < 4; rt++) {
      int i0 = row0 + wr * 64 + rt * 16 + quad * 4;
      f32x4 a = acc[rt][ct];
#pragma unroll
      for (int r = 0; r < 4; r++) out[(i0 + r) * 1024 + j] = a[r] + bias;
    }
  }
}

extern "C" void kernel_launch(void* const* d_in, const int* in_sizes, int n_in,
                              void* d_out, int out_size, void* d_ws, size_t ws_size,
                              hipStream_t stream) {
  const float* x   = (const float*)d_in[0];
  // d_in[1] mask, d_in[2] w_q, d_in[3] w_k: dead per reference semantics
  const float* wv  = (const float*)d_in[4];
  const float* fcw = (const float*)d_in[5];
  const float* fcb = (const float*)d_in[6];
  float* out = (float*)d_out;

  char* ws = (char*)d_ws;
  unsigned short* xb  = (unsigned short*)(ws);              // 16 MB (8192x1024 bf16)
  unsigned short* wcT = (unsigned short*)(ws + 16777216);   // 2 MB  (1024x1024 bf16)

  prep<<<512, 256, 0, stream>>>(x, wv, fcw, xb, wcT);
  final_gemm<<<1024, 256, 0, stream>>>(xb, wcT, fcb, out);
}